// Round 2
// baseline (567.960 us; speedup 1.0000x reference)
//
#include <hip/hip_runtime.h>
#include <math.h>

// DiffDispatchLP: batched (256x) PDHG, 400 iters.
// R2: ONE WAVE PER ITEM (grid 256 x block 64). All roles looped over lane-
// chunks inside a single wave; no s_barrier (block == 1 wave; __syncthreads
// degenerates to the lgkmcnt drain). Removes: 2x 8-wave barrier arrival
// spread, synchronized post-barrier LDS bursts, the TC LDS round-trip
// (total-charge dual is now a wave-uniform register), and s_red.
// Cost: all issue on 1 SIMD -> issue-bound ~700-900 cy/iter vs 1325 now.
//
// sy layout (dwords) unchanged, regions = [4 guard][data] stride 104:
//   VB[v] at 624v: MD1@0 MD2@104 MD3@208 MS@312 BY@416 SW@520   (v=0,1)
//   EQ@1248  BS@1352  BCD@1456 (c@1456,d@1560)  UC@1664 (uc,ud)
// sxb layout: C@0 D@104 YC@208 YD@312 S@416  (slot = region + 4 + t)

#define NITER 400
#define PITER 10
#define NY 1874
#define NX 520

// Full wave64 sum via DPP (VALU pipe). row_shr 1/2/4/8 fold each 16-lane row
// (bound_ctrl=1 zero-fills), row_bcast:15 -> rows 1,3, row_bcast:31 -> rows
// 2,3; lane 63 holds the total; broadcast via readlane.
__device__ __forceinline__ float wave_sum64(float v) {
  float r = v;
  int x;
  x = __builtin_amdgcn_update_dpp(0, __float_as_int(r), 0x111, 0xf, 0xf, true);
  r += __int_as_float(x);
  x = __builtin_amdgcn_update_dpp(0, __float_as_int(r), 0x112, 0xf, 0xf, true);
  r += __int_as_float(x);
  x = __builtin_amdgcn_update_dpp(0, __float_as_int(r), 0x114, 0xf, 0xf, true);
  r += __int_as_float(x);
  x = __builtin_amdgcn_update_dpp(0, __float_as_int(r), 0x118, 0xf, 0xf, true);
  r += __int_as_float(x);
  x = __builtin_amdgcn_update_dpp(0, __float_as_int(r), 0x142, 0xa, 0xf, true);
  r += __int_as_float(x);
  x = __builtin_amdgcn_update_dpp(0, __float_as_int(r), 0x143, 0xc, 0xf, true);
  r += __int_as_float(x);
  return __int_as_float(__builtin_amdgcn_readlane(__float_as_int(r), 63));
}

__global__ __launch_bounds__(64, 1)
void lp_solve_kernel(const float* __restrict__ price, float* __restrict__ out) {
  __shared__ float sy[NY];
  __shared__ float sxb[NX];

  const int lane = threadIdx.x;   // 0..63 (one wave)
  const int bi = blockIdx.x;
  const double ETA_D = sqrt(0.91);
  const float cET = (float)(-(ETA_D * 0.25));  // -ETA*DT
  const float cDE = (float)(0.25 / ETA_D);     // DT/ETA

  // ---------------- per-lane chunk constants ----------------
  // x columns: j = 2*v + s; v=0..4 (c,d,yc,yd,soc); s=0: t=lane, s=1: t=64+lane (lane<32)
  const int ts_[2] = { lane, (lane < 32) ? 64 + lane : 95 };  // clamped for safety
  const bool actS1 = (lane < 32);

  // MD chunks k=0..2: i = 64k+lane, rows i<190; (v,t) = (i>=95, i-95*(i>=95))
  int mx_[3], mw_[3];
  float cv2_[3], cv3_[3];
  bool mact_[3];
#pragma unroll
  for (int k = 0; k < 3; ++k) {
    int i = 64 * k + lane;
    bool act = (i < 190);
    mact_[k] = act;
    int mi = act ? i : 189;
    int mv = (mi >= 95) ? 1 : 0;
    int mt = mi - 95 * mv;
    mx_[k] = 104 * (2 + mv) + mt;   // sxb y_v base
    mw_[k] = 624 * mv + mt;         // sy VB[v] write base
    cv2_[k] = (mt <= 93) ? 1.f : 0.f;
    cv3_[k] = (mt <= 92) ? 1.f : 0.f;
  }
  // RAMP chunks: k0 t=1..64 (all lanes); k1 t=65..95 (lane<31, clamp)
  const int rt_[2] = { 1 + lane, 65 + ((lane < 31) ? lane : 30) };
  const bool ract_[2] = { true, lane < 31 };
  // SW chunks: k0 t=0..63; k1 t=64..94 (lane<31, clamp)
  const int st_[2] = { lane, 64 + ((lane < 31) ? lane : 30) };
  const bool sact_[2] = { true, lane < 31 };
  // EQ chunks: k0 r=0..63; k1 r=64..96 (lane<=32, clamp to 96)
  const int er_[2] = { lane, 64 + ((lane < 32) ? lane : 32) };
  const float cEb_[2] = { 1.f, (lane >= 32) ? -1.f : 1.f };  // r=96 -> -1
  const bool eact_[2] = { true, lane <= 32 };
  // BOX chunks: k0 t=0..63; k1 t=64..95 (write lane<32)
  const int tb_[2] = { lane, 64 + (lane & 31) };
  const bool bact_[2] = { true, lane < 32 };

  // ---------------- state ----------------
  float xA[10];
  float q_[10];
#pragma unroll
  for (int j = 0; j < 10; ++j) { xA[j] = 0.f; q_[j] = 0.f; }
  float yb[2][13], ym[3][3], yr[2][4], ysw[2][2], yeq[2];
#pragma unroll
  for (int s = 0; s < 2; ++s) {
#pragma unroll
    for (int j = 0; j < 13; ++j) yb[s][j] = 0.f;
#pragma unroll
    for (int j = 0; j < 4; ++j) yr[s][j] = 0.f;
    ysw[s][0] = 0.f; ysw[s][1] = 0.f; yeq[s] = 0.f;
  }
#pragma unroll
  for (int k = 0; k < 3; ++k) { ym[k][0] = 0.f; ym[k][1] = 0.f; ym[k][2] = 0.f; }
  float ytc = 0.f;     // total-charge dual (wave-uniform register, no LDS)
  float tcval = 0.f;   // value seen by c-gather
  float tauv = 0.f, sigv = 0.f;

  // ---------------- gather all 10 x-columns ----------------
  auto gatherAll = [&](float (&g)[10]) {
    // c,d: j = 2*v01 + s
#pragma unroll
    for (int v01 = 0; v01 < 2; ++v01) {
      const float ce = v01 ? cDE : cET;
      const float ct = v01 ? 0.f : 0.25f;
#pragma unroll
      for (int s = 0; s < 2; ++s) {
        const int t = ts_[s];
        float b  = sy[1460 + 104 * v01 + t];
        float e  = sy[1252 + t];
        float um = sy[1667 + 104 * v01 + t];
        float up = sy[1668 + 104 * v01 + t];
        g[2 * v01 + s] = b + ce * e + um - up + ct * tcval;
      }
    }
    // yc,yd: j = 4 + 2*yv + s
#pragma unroll
    for (int yv = 0; yv < 2; ++yv) {
#pragma unroll
      for (int s = 0; s < 2; ++s) {
        const int bv = 624 * yv + ts_[s];
        const int bw = 624 * (1 - yv) + ts_[s];
        float k1 = sy[bv + 3], k2 = sy[bv + 106], k3 = sy[bv + 209];
        float m0 = sy[bv + 316], m1 = sy[bv + 317];
        float bY = sy[bv + 420], s0 = sy[bv + 524], s1 = sy[bw + 523];
        g[4 + 2 * yv + s] = bY + s0 + s1 + (m0 - m1) - (k1 + k2 + k3);
      }
    }
    // soc: j = 8 + s
#pragma unroll
    for (int s = 0; s < 2; ++s) {
      const int t = ts_[s];
      float e0 = sy[1252 + t], e1 = sy[1253 + t], bS = sy[1356 + t];
      const float ce1 = (t <= 94) ? -1.f : 1.f;
      g[8 + s] = bS + e0 + ce1 * e1;
    }
  };

  // ---------------- phase B: dual update / raw dots, one wave ----------------
  auto phaseB = [&](bool power) {
    const float sig = sigv;
    // BOX
#pragma unroll
    for (int s = 0; s < 2; ++s) {
      const int tb = tb_[s];
      float c_ = sxb[4 + tb], d_ = sxb[108 + tb];
      float yc_ = sxb[212 + tb], yd_ = sxb[316 + tb], s_ = sxb[420 + tb];
      float v0, v1, v2, v3, v4, v5, v6, v7, v8, v9, v10, v11, v12;
      if (power) {
        v0 = c_; v1 = d_; v2 = -c_; v3 = -d_; v4 = -yc_; v5 = yc_;
        v6 = -yd_; v7 = yd_; v8 = -s_; v9 = s_; v10 = yc_ + yd_;
        v11 = c_ - 195.f * yc_; v12 = d_ - 195.f * yd_;
      } else {
        yb[s][0]  = fmaxf(yb[s][0]  + sig * (c_  - 195.f), 0.f);      v0 = yb[s][0];
        yb[s][1]  = fmaxf(yb[s][1]  + sig * (d_  - 195.f), 0.f);      v1 = yb[s][1];
        yb[s][2]  = fmaxf(yb[s][2]  - sig * c_,            0.f);      v2 = yb[s][2];
        yb[s][3]  = fmaxf(yb[s][3]  - sig * d_,            0.f);      v3 = yb[s][3];
        yb[s][4]  = fmaxf(yb[s][4]  - sig * yc_,           0.f);      v4 = yb[s][4];
        yb[s][5]  = fmaxf(yb[s][5]  + sig * (yc_ - 1.f),   0.f);      v5 = yb[s][5];
        yb[s][6]  = fmaxf(yb[s][6]  - sig * yd_,           0.f);      v6 = yb[s][6];
        yb[s][7]  = fmaxf(yb[s][7]  + sig * (yd_ - 1.f),   0.f);      v7 = yb[s][7];
        yb[s][8]  = fmaxf(yb[s][8]  - sig * s_,            0.f);      v8 = yb[s][8];
        yb[s][9]  = fmaxf(yb[s][9]  + sig * (s_ - 800.f),  0.f);      v9 = yb[s][9];
        yb[s][10] = fmaxf(yb[s][10] + sig * (yc_ + yd_ - 1.f), 0.f);  v10 = yb[s][10];
        yb[s][11] = fmaxf(yb[s][11] + sig * (c_ - 195.f * yc_), 0.f); v11 = yb[s][11];
        yb[s][12] = fmaxf(yb[s][12] + sig * (d_ - 195.f * yd_), 0.f); v12 = yb[s][12];
      }
      if (bact_[s]) {
        sy[1460 + tb] = v0 - v2 + v11;                     // bC
        sy[1564 + tb] = v1 - v3 + v12;                     // bD
        sy[420 + tb]  = -v4 + v5 + v10 - 195.f * v11;      // bYC
        sy[1044 + tb] = -v6 + v7 + v10 - 195.f * v12;      // bYD
        sy[1356 + tb] = -v8 + v9;                          // bS
      }
    }
    // MIN-DURATION
#pragma unroll
    for (int k = 0; k < 3; ++k) {
      const int mx = mx_[k], mw = mw_[k];
      float mp = sxb[mx + 3];
      float mc = sxb[mx + 4], m1v = sxb[mx + 5];
      float m2v = sxb[mx + 6], m3v = sxb[mx + 7];
      float base = mc - mp;
      float d1 = base - m1v, d2 = base - m2v, d3 = base - m3v;
      float o1, o2, o3;
      if (power) { o1 = d1; o2 = d2; o3 = d3; }
      else {
        ym[k][0] = fmaxf(ym[k][0] + sig * d1, 0.f); o1 = ym[k][0];
        ym[k][1] = fmaxf(ym[k][1] + sig * d2, 0.f); o2 = ym[k][1];
        ym[k][2] = fmaxf(ym[k][2] + sig * d3, 0.f); o3 = ym[k][2];
      }
      if (mact_[k]) {
        sy[mw + 4]   = o1;
        sy[mw + 108] = o2;
        sy[mw + 212] = o3;
        sy[mw + 316] = o1 + cv2_[k] * o2 + cv3_[k] * o3;   // own-sum
      }
    }
    // RAMP
#pragma unroll
    for (int k = 0; k < 2; ++k) {
      const int rt = rt_[k];
      float rcm = sxb[3 + rt], rc0 = sxb[4 + rt];
      float rdm = sxb[107 + rt], rd0 = sxb[108 + rt];
      float u0, u1, u2, u3;
      if (power) { u0 = rc0 - rcm; u1 = rcm - rc0; u2 = rd0 - rdm; u3 = rdm - rd0; }
      else {
        yr[k][0] = fmaxf(yr[k][0] + sig * (rc0 - rcm - 65.f), 0.f); u0 = yr[k][0];
        yr[k][1] = fmaxf(yr[k][1] + sig * (rcm - rc0 - 65.f), 0.f); u1 = yr[k][1];
        yr[k][2] = fmaxf(yr[k][2] + sig * (rd0 - rdm - 65.f), 0.f); u2 = yr[k][2];
        yr[k][3] = fmaxf(yr[k][3] + sig * (rdm - rd0 - 65.f), 0.f); u3 = yr[k][3];
      }
      if (ract_[k]) { sy[1667 + rt] = u0 - u1; sy[1771 + rt] = u2 - u3; }
    }
    // SWITCH
#pragma unroll
    for (int k = 0; k < 2; ++k) {
      const int st = st_[k];
      float a0 = sxb[212 + st], a1 = sxb[213 + st];
      float b0 = sxb[316 + st], b1 = sxb[317 + st];
      float p0, p1;
      if (power) { p0 = a0 + b1; p1 = b0 + a1; }
      else {
        ysw[k][0] = fmaxf(ysw[k][0] + sig * (a0 + b1 - 1.f), 0.f); p0 = ysw[k][0];
        ysw[k][1] = fmaxf(ysw[k][1] + sig * (b0 + a1 - 1.f), 0.f); p1 = ysw[k][1];
      }
      if (sact_[k]) { sy[524 + st] = p0; sy[1148 + st] = p1; }
    }
    // EQUALITY (free dual)
#pragma unroll
    for (int k = 0; k < 2; ++k) {
      const int er = er_[k];
      float ep = sxb[419 + er], ecur = sxb[420 + er];
      float exc = sxb[4 + er], exd = sxb[108 + er];
      float dot = ecur - cEb_[k] * ep + cET * exc + cDE * exd;
      float ev;
      if (power) ev = dot;
      else { yeq[k] += sig * dot; ev = yeq[k]; }
      if (eact_[k]) sy[1252 + er] = ev;
    }
    // TOTAL-CHARGE: wave-uniform register, no LDS round trip
    {
      float ssum = sxb[4 + lane] + ((lane < 32) ? sxb[68 + lane] : 0.f);
      float tot = wave_sum64(ssum);
      if (power) tcval = 0.25f * tot;
      else { ytc = fmaxf(ytc + sig * (0.25f * tot - 1200.f), 0.f); tcval = ytc; }
    }
  };

  // ================= power iteration: ||K||_2 =================
  for (int i = lane; i < NY; i += 64) sy[i] = 0.f;
  for (int i = lane; i < NX; i += 64) sxb[i] = 0.f;
  __syncthreads();
#pragma unroll
  for (int j = 0; j < 10; ++j) {
    const bool act = ((j & 1) == 0) || actS1;
    if (act) sxb[104 * (j >> 1) + 4 + ts_[j & 1]] = 1.f;
  }
  __syncthreads();

  float lam2 = 1.f;
  for (int pit = 0; pit < PITER; ++pit) {
    phaseB(true);                        // sy = combined(K v), tcval raw
    __syncthreads();
    float g[10];
    gatherAll(g);                        // (K^T K v) per column
    float part = 0.f;
#pragma unroll
    for (int j = 0; j < 10; ++j) {
      const bool act = ((j & 1) == 0) || actS1;
      if (act) part += g[j] * g[j];
    }
    lam2 = sqrtf(wave_sum64(part));
    float inv = 1.f / lam2;
#pragma unroll
    for (int j = 0; j < 10; ++j) {
      const bool act = ((j & 1) == 0) || actS1;
      if (act) sxb[104 * (j >> 1) + 4 + ts_[j & 1]] = g[j] * inv;
    }
    __syncthreads();
  }
  tauv = (float)(0.9 / sqrt((double)lam2));
  sigv = tauv;

  // ================= PDHG =================
  for (int i = lane; i < NY; i += 64) sy[i] = 0.f;
  tcval = 0.f;
  {
    float p0 = price[bi * 96 + lane];
    q_[0] = 0.25f * p0;            // c, t=lane
    q_[2] = -0.25f * p0;           // d, t=lane
    if (actS1) {
      float p1 = price[bi * 96 + 64 + lane];
      q_[1] = 0.25f * p1;          // c, t=64+lane
      q_[3] = -0.25f * p1;         // d, t=64+lane
    }
  }
  __syncthreads();

#pragma unroll 1
  for (int it = 0; it < NITER; ++it) {
    float g[10];
    gatherAll(g);
#pragma unroll
    for (int j = 0; j < 10; ++j) {
      const bool act = ((j & 1) == 0) || actS1;
      if (act) {
        float xa = xA[j] - tauv * (q_[j] + g[j]);
        sxb[104 * (j >> 1) + 4 + ts_[j & 1]] = 2.f * xa - xA[j];
        xA[j] = xa;
      }
    }
    __syncthreads();
    phaseB(false);
    __syncthreads();
  }

  // output: c then d, each (256,96)
  out[bi * 96 + lane] = xA[0];
  if (actS1) out[bi * 96 + 64 + lane] = xA[1];
  out[24576 + bi * 96 + lane] = xA[2];
  if (actS1) out[24576 + bi * 96 + 64 + lane] = xA[3];
}

extern "C" void kernel_launch(void* const* d_in, const int* in_sizes, int n_in,
                              void* d_out, int out_size, void* d_ws, size_t ws_size,
                              hipStream_t stream) {
  const float* price = (const float*)d_in[0];
  float* outp = (float*)d_out;
  hipLaunchKernelGGL(lp_solve_kernel, dim3(256), dim3(64), 0, stream, price, outp);
}

// Round 3
// 296.293 us; speedup vs baseline: 1.9169x; 1.9169x over previous
//
#include <hip/hip_runtime.h>
#include <math.h>

// DiffDispatchLP: batched (256x) PDHG, 400 iters.
// R3: FOUR WAVES PER ITEM (grid 256 x block 256), midpoint between
// R1 (8 waves, 221us, barrier-spread-bound) and R2 (1 wave, 525us,
// issue/latency-serialization-bound). Each wave owns 2 column-chunks in
// phase A (2x the per-wave ILP of R1, enough independent LDS reads to
// hide latency) and a balanced row-chunk set in phase B:
//   wid0: BOX t0-63   + total-charge (in-register, only wid0's c-cols use it)
//   wid1: BOX t64-95
//   wid2: MIN-DURATION x3
//   wid3: RAMP x2 + SWITCH x2 + EQUALITY x2
// Two 4-arrival barriers per iteration (minimum for the bipartite dep).
//
// sy layout (dwords) unchanged, regions = [4 guard][data] stride 104:
//   VB[v] at 624v: MD1@0 MD2@104 MD3@208 MS@312 BY@416 SW@520   (v=0,1)
//   EQ@1248  BS@1352  BCD@1456 (c@1456,d@1560)  UC@1664 (uc,ud)
// sxb layout: C@0 D@104 YC@208 YD@312 S@416  (slot = region + 4 + t)

#define NITER 400
#define PITER 10
#define NY 1874
#define NX 520

// Full wave64 sum via DPP (VALU pipe). row_shr 1/2/4/8 fold each 16-lane row
// (bound_ctrl=1 zero-fills), row_bcast:15 -> rows 1,3, row_bcast:31 -> rows
// 2,3; lane 63 holds the total; broadcast via readlane.
__device__ __forceinline__ float wave_sum64(float v) {
  float r = v;
  int x;
  x = __builtin_amdgcn_update_dpp(0, __float_as_int(r), 0x111, 0xf, 0xf, true);
  r += __int_as_float(x);
  x = __builtin_amdgcn_update_dpp(0, __float_as_int(r), 0x112, 0xf, 0xf, true);
  r += __int_as_float(x);
  x = __builtin_amdgcn_update_dpp(0, __float_as_int(r), 0x114, 0xf, 0xf, true);
  r += __int_as_float(x);
  x = __builtin_amdgcn_update_dpp(0, __float_as_int(r), 0x118, 0xf, 0xf, true);
  r += __int_as_float(x);
  x = __builtin_amdgcn_update_dpp(0, __float_as_int(r), 0x142, 0xa, 0xf, true);
  r += __int_as_float(x);
  x = __builtin_amdgcn_update_dpp(0, __float_as_int(r), 0x143, 0xc, 0xf, true);
  r += __int_as_float(x);
  return __int_as_float(__builtin_amdgcn_readlane(__float_as_int(r), 63));
}

__global__ __launch_bounds__(256, 1)
void lp_solve_kernel(const float* __restrict__ price, float* __restrict__ out) {
  __shared__ float sy[NY];
  __shared__ float sxb[NX];
  __shared__ float s_red[4];

  const int tid = threadIdx.x, lane = tid & 63, wid = tid >> 6;
  const int bi = blockIdx.x;
  const double ETA_D = sqrt(0.91);
  const float cET = (float)(-(ETA_D * 0.25));  // -ETA*DT
  const float cDE = (float)(0.25 / ETA_D);     // DT/ETA

  // ---------------- phase A slot constants (2 column slots / wave) ----------
  // slot bases: cd body {iA=bBC, iB=bEQ, iC=bUM, cF=ce, cG=ctc}
  //             y  body {iA=bv,  iB=bw}
  //             soc body {iA=bEQ, iB=bBS, cF=ce1}
  int iA0 = 0, iB0 = 0, iC0 = 0, iA1 = 0, iB1 = 0, iC1 = 0, wX0 = 0, wX1 = 0;
  float cF0 = 0.f, cG0 = 0.f, cF1 = 0.f, cG1 = 0.f, q0 = 0.f, q1 = 0.f;
  bool act1 = true;

  auto setCD = [&](int col, int& iA, int& iB, int& iC, float& cF, float& cG,
                   int& wX, float& q) {
    const int v01 = (col >= 96) ? 1 : 0;
    const int t = col - 96 * v01;
    iA = 1460 + 104 * v01 + t;
    iB = 1252 + t;
    iC = 1667 + 104 * v01 + t;
    cF = v01 ? cDE : cET;
    cG = v01 ? 0.f : 0.25f;
    wX = 104 * v01 + 4 + t;
    q = (v01 ? -0.25f : 0.25f) * price[bi * 96 + t];
  };
  auto setY = [&](int col, int& iA, int& iB, int& wX) {
    const int yv = (col >= 288) ? 1 : 0;
    const int t = col - 192 - 96 * yv;
    iA = 624 * yv + t;
    iB = 624 * (1 - yv) + t;
    wX = 104 * (2 + yv) + 4 + t;
  };
  auto setSOC = [&](int col, int& iA, int& iB, float& cF, int& wX) {
    const int t = col - 384;
    iA = 1252 + t;
    iB = 1356 + t;
    cF = (t <= 94) ? -1.f : 1.f;
    wX = 420 + t;
  };

  if (wid == 0) {
    setCD(lane, iA0, iB0, iC0, cF0, cG0, wX0, q0);
    setCD(64 + lane, iA1, iB1, iC1, cF1, cG1, wX1, q1);
  } else if (wid == 1) {
    setCD(128 + lane, iA0, iB0, iC0, cF0, cG0, wX0, q0);
    setY(192 + lane, iA1, iB1, wX1);
  } else if (wid == 2) {
    setY(256 + lane, iA0, iB0, wX0);
    setY(320 + lane, iA1, iB1, wX1);
  } else {
    setSOC(384 + lane, iA0, iB0, cF0, wX0);
    const int c1 = (lane < 32) ? 448 + lane : 479;  // clamp (reads land in data/guard)
    setSOC(c1, iA1, iB1, cF1, wX1);
    act1 = (lane < 32);
  }

  // ---------------- phase B constants ----------------
  // BOX (wid 0,1)
  const int tbB = (wid == 0) ? lane : 64 + (lane & 31);
  const bool bact = (wid == 0) || (lane < 32);
  // MD (wid 2): 3 chunks i = 64k+lane, rows i<190
  int mx_[3], mw_[3];
  float cv2_[3], cv3_[3];
  bool mact_[3];
#pragma unroll
  for (int k = 0; k < 3; ++k) {
    const int i = 64 * k + lane;
    const bool act = (i < 190);
    mact_[k] = act;
    const int mi = act ? i : 189;
    const int mv = (mi >= 95) ? 1 : 0;
    const int mt = mi - 95 * mv;
    mx_[k] = 104 * (2 + mv) + mt;
    mw_[k] = 624 * mv + mt;
    cv2_[k] = (mt <= 93) ? 1.f : 0.f;
    cv3_[k] = (mt <= 92) ? 1.f : 0.f;
  }
  // RAMP / SW / EQ (wid 3)
  const int rt0 = 1 + lane, rt1 = 65 + ((lane < 31) ? lane : 30);
  const bool ra1 = (lane < 31);
  const int st0 = lane, st1 = 64 + ((lane < 31) ? lane : 30);
  const bool sa1 = (lane < 31);
  const int er0 = lane, er1 = 64 + ((lane < 32) ? lane : 32);
  const float cEb1 = (lane >= 32) ? -1.f : 1.f;  // r=96 row: dot = +s[95]
  const bool ea1 = (lane <= 32);

  // ---------------- state ----------------
  float xA0 = 0.f, xA1 = 0.f;
  float yb0=0,yb1=0,yb2=0,yb3=0,yb4=0,yb5=0,yb6=0,yb7=0,yb8=0,yb9=0,yb10=0,yb11=0,yb12=0;
  float ym[3][3];
#pragma unroll
  for (int k = 0; k < 3; ++k) { ym[k][0]=0.f; ym[k][1]=0.f; ym[k][2]=0.f; }
  float yr0_[4] = {0,0,0,0}, yr1_[4] = {0,0,0,0};
  float ysw00=0, ysw01=0, ysw10=0, ysw11=0, yeq0=0, yeq1=0;
  float ytc = 0.f;     // total-charge dual (register; only wid0's c-cols use it)
  float tcval = 0.f;
  float tauv = 0.f, sigv = 0.f;

  // ---------------- gather bodies ----------------
  auto g_cd = [&](int iA, int iB, int iC, float ce, float ct) -> float {
    return sy[iA] + ce * sy[iB] + sy[iC] - sy[iC + 1] + ct * tcval;
  };
  auto g_y = [&](int bv, int bw) -> float {
    float k1 = sy[bv + 3], k2 = sy[bv + 106], k3 = sy[bv + 209];
    float m0 = sy[bv + 316], m1 = sy[bv + 317];
    float bY = sy[bv + 420], s0 = sy[bv + 524], s1 = sy[bw + 523];
    return bY + s0 + s1 + (m0 - m1) - (k1 + k2 + k3);
  };
  auto g_soc = [&](int iA, int iB, float ce1) -> float {
    return sy[iB] + sy[iA] + ce1 * sy[iA + 1];
  };

  // ---------------- phase B ----------------
  auto phaseB = [&](bool power) {
    const float sig = sigv;
    if (wid <= 1) {  // BOX (+TC on wid0)
      float c_ = sxb[4 + tbB], d_ = sxb[108 + tbB];
      float yc_ = sxb[212 + tbB], yd_ = sxb[316 + tbB], s_ = sxb[420 + tbB];
      float v0, v1, v2, v3, v4, v5, v6, v7, v8, v9, v10, v11, v12;
      if (power) {
        v0 = c_; v1 = d_; v2 = -c_; v3 = -d_; v4 = -yc_; v5 = yc_;
        v6 = -yd_; v7 = yd_; v8 = -s_; v9 = s_; v10 = yc_ + yd_;
        v11 = c_ - 195.f * yc_; v12 = d_ - 195.f * yd_;
      } else {
        yb0  = fmaxf(yb0  + sig * (c_  - 195.f), 0.f);      v0 = yb0;
        yb1  = fmaxf(yb1  + sig * (d_  - 195.f), 0.f);      v1 = yb1;
        yb2  = fmaxf(yb2  - sig * c_,            0.f);      v2 = yb2;
        yb3  = fmaxf(yb3  - sig * d_,            0.f);      v3 = yb3;
        yb4  = fmaxf(yb4  - sig * yc_,           0.f);      v4 = yb4;
        yb5  = fmaxf(yb5  + sig * (yc_ - 1.f),   0.f);      v5 = yb5;
        yb6  = fmaxf(yb6  - sig * yd_,           0.f);      v6 = yb6;
        yb7  = fmaxf(yb7  + sig * (yd_ - 1.f),   0.f);      v7 = yb7;
        yb8  = fmaxf(yb8  - sig * s_,            0.f);      v8 = yb8;
        yb9  = fmaxf(yb9  + sig * (s_ - 800.f),  0.f);      v9 = yb9;
        yb10 = fmaxf(yb10 + sig * (yc_ + yd_ - 1.f), 0.f);  v10 = yb10;
        yb11 = fmaxf(yb11 + sig * (c_ - 195.f * yc_), 0.f); v11 = yb11;
        yb12 = fmaxf(yb12 + sig * (d_ - 195.f * yd_), 0.f); v12 = yb12;
      }
      if (bact) {
        sy[1460 + tbB] = v0 - v2 + v11;                     // bC
        sy[1564 + tbB] = v1 - v3 + v12;                     // bD
        sy[420 + tbB]  = -v4 + v5 + v10 - 195.f * v11;      // bYC
        sy[1044 + tbB] = -v6 + v7 + v10 - 195.f * v12;      // bYD
        sy[1356 + tbB] = -v8 + v9;                          // bS
      }
      if (wid == 0) {  // TOTAL-CHARGE, register-resident
        float ssum = sxb[4 + lane] + ((lane < 32) ? sxb[68 + lane] : 0.f);
        float tot = wave_sum64(ssum);
        if (power) tcval = 0.25f * tot;
        else { ytc = fmaxf(ytc + sig * (0.25f * tot - 1200.f), 0.f); tcval = ytc; }
      }
    } else if (wid == 2) {  // MIN-DURATION x3
#pragma unroll
      for (int k = 0; k < 3; ++k) {
        const int mx = mx_[k], mw = mw_[k];
        float mp = sxb[mx + 3];
        float mc = sxb[mx + 4], m1v = sxb[mx + 5];
        float m2v = sxb[mx + 6], m3v = sxb[mx + 7];
        float base = mc - mp;
        float d1 = base - m1v, d2 = base - m2v, d3 = base - m3v;
        float o1, o2, o3;
        if (power) { o1 = d1; o2 = d2; o3 = d3; }
        else {
          ym[k][0] = fmaxf(ym[k][0] + sig * d1, 0.f); o1 = ym[k][0];
          ym[k][1] = fmaxf(ym[k][1] + sig * d2, 0.f); o2 = ym[k][1];
          ym[k][2] = fmaxf(ym[k][2] + sig * d3, 0.f); o3 = ym[k][2];
        }
        if (mact_[k]) {
          sy[mw + 4]   = o1;
          sy[mw + 108] = o2;
          sy[mw + 212] = o3;
          sy[mw + 316] = o1 + cv2_[k] * o2 + cv3_[k] * o3;   // own-sum
        }
      }
    } else {  // RAMP x2 + SWITCH x2 + EQUALITY x2
      {  // RAMP chunk 0 (t=1..64)
        float rcm = sxb[3 + rt0], rc0 = sxb[4 + rt0];
        float rdm = sxb[107 + rt0], rd0 = sxb[108 + rt0];
        float u0, u1, u2, u3;
        if (power) { u0 = rc0 - rcm; u1 = rcm - rc0; u2 = rd0 - rdm; u3 = rdm - rd0; }
        else {
          yr0_[0] = fmaxf(yr0_[0] + sig * (rc0 - rcm - 65.f), 0.f); u0 = yr0_[0];
          yr0_[1] = fmaxf(yr0_[1] + sig * (rcm - rc0 - 65.f), 0.f); u1 = yr0_[1];
          yr0_[2] = fmaxf(yr0_[2] + sig * (rd0 - rdm - 65.f), 0.f); u2 = yr0_[2];
          yr0_[3] = fmaxf(yr0_[3] + sig * (rdm - rd0 - 65.f), 0.f); u3 = yr0_[3];
        }
        sy[1667 + rt0] = u0 - u1; sy[1771 + rt0] = u2 - u3;
      }
      {  // RAMP chunk 1 (t=65..95)
        float rcm = sxb[3 + rt1], rc0 = sxb[4 + rt1];
        float rdm = sxb[107 + rt1], rd0 = sxb[108 + rt1];
        float u0, u1, u2, u3;
        if (power) { u0 = rc0 - rcm; u1 = rcm - rc0; u2 = rd0 - rdm; u3 = rdm - rd0; }
        else {
          yr1_[0] = fmaxf(yr1_[0] + sig * (rc0 - rcm - 65.f), 0.f); u0 = yr1_[0];
          yr1_[1] = fmaxf(yr1_[1] + sig * (rcm - rc0 - 65.f), 0.f); u1 = yr1_[1];
          yr1_[2] = fmaxf(yr1_[2] + sig * (rd0 - rdm - 65.f), 0.f); u2 = yr1_[2];
          yr1_[3] = fmaxf(yr1_[3] + sig * (rdm - rd0 - 65.f), 0.f); u3 = yr1_[3];
        }
        if (ra1) { sy[1667 + rt1] = u0 - u1; sy[1771 + rt1] = u2 - u3; }
      }
      {  // SWITCH chunks
        float a0 = sxb[212 + st0], a1 = sxb[213 + st0];
        float b0 = sxb[316 + st0], b1 = sxb[317 + st0];
        float p0, p1;
        if (power) { p0 = a0 + b1; p1 = b0 + a1; }
        else {
          ysw00 = fmaxf(ysw00 + sig * (a0 + b1 - 1.f), 0.f); p0 = ysw00;
          ysw01 = fmaxf(ysw01 + sig * (b0 + a1 - 1.f), 0.f); p1 = ysw01;
        }
        sy[524 + st0] = p0; sy[1148 + st0] = p1;
        float a0b = sxb[212 + st1], a1b = sxb[213 + st1];
        float b0b = sxb[316 + st1], b1b = sxb[317 + st1];
        float p0b, p1b;
        if (power) { p0b = a0b + b1b; p1b = b0b + a1b; }
        else {
          ysw10 = fmaxf(ysw10 + sig * (a0b + b1b - 1.f), 0.f); p0b = ysw10;
          ysw11 = fmaxf(ysw11 + sig * (b0b + a1b - 1.f), 0.f); p1b = ysw11;
        }
        if (sa1) { sy[524 + st1] = p0b; sy[1148 + st1] = p1b; }
      }
      {  // EQUALITY chunks (free dual)
        float ep = sxb[419 + er0], ecur = sxb[420 + er0];
        float exc = sxb[4 + er0], exd = sxb[108 + er0];
        float dot = ecur - ep + cET * exc + cDE * exd;
        float ev;
        if (power) ev = dot;
        else { yeq0 += sig * dot; ev = yeq0; }
        sy[1252 + er0] = ev;
        float epb = sxb[419 + er1], ecurb = sxb[420 + er1];
        float excb = sxb[4 + er1], exdb = sxb[108 + er1];
        float dotb = ecurb - cEb1 * epb + cET * excb + cDE * exdb;
        float evb;
        if (power) evb = dotb;
        else { yeq1 += sig * dotb; evb = yeq1; }
        if (ea1) sy[1252 + er1] = evb;
      }
    }
  };

  // ---------------- gather dispatch ----------------
  auto gather2 = [&](float& g0, float& g1) {
    if (wid == 0)      { g0 = g_cd(iA0, iB0, iC0, cF0, cG0); g1 = g_cd(iA1, iB1, iC1, cF1, cG1); }
    else if (wid == 1) { g0 = g_cd(iA0, iB0, iC0, cF0, cG0); g1 = g_y(iA1, iB1); }
    else if (wid == 2) { g0 = g_y(iA0, iB0);                 g1 = g_y(iA1, iB1); }
    else               { g0 = g_soc(iA0, iB0, cF0);          g1 = g_soc(iA1, iB1, cF1); }
  };

  // ================= power iteration: ||K||_2 =================
  for (int i = tid; i < NY; i += 256) sy[i] = 0.f;
  for (int i = tid; i < NX; i += 256) sxb[i] = 0.f;
  __syncthreads();
  sxb[wX0] = 1.f;
  if (act1) sxb[wX1] = 1.f;
  __syncthreads();

  float lam2 = 1.f;
  for (int pit = 0; pit < PITER; ++pit) {
    phaseB(true);                        // sy = combined(K v); tcval raw on wid0
    __syncthreads();
    float g0, g1;
    gather2(g0, g1);                     // (K^T K v) per column
    float part = g0 * g0 + (act1 ? g1 * g1 : 0.f);
    part = wave_sum64(part);
    if (lane == 0) s_red[wid] = part;
    __syncthreads();
    lam2 = sqrtf(s_red[0] + s_red[1] + s_red[2] + s_red[3]);
    float inv = 1.f / lam2;
    sxb[wX0] = g0 * inv;
    if (act1) sxb[wX1] = g1 * inv;
    __syncthreads();
  }
  tauv = (float)(0.9 / sqrt((double)lam2));
  sigv = tauv;

  // ================= PDHG =================
  for (int i = tid; i < NY; i += 256) sy[i] = 0.f;
  tcval = 0.f;
  __syncthreads();

#pragma unroll 1
  for (int it = 0; it < NITER; ++it) {
    float g0, g1;
    gather2(g0, g1);
    {
      float xa = xA0 - tauv * (q0 + g0);
      sxb[wX0] = 2.f * xa - xA0;
      xA0 = xa;
    }
    if (act1) {
      float xa = xA1 - tauv * (q1 + g1);
      sxb[wX1] = 2.f * xa - xA1;
      xA1 = xa;
    }
    __syncthreads();
    phaseB(false);
    __syncthreads();
  }

  // output: c then d, each (256,96)
  if (wid == 0) {
    out[bi * 96 + lane] = xA0;                       // c t=0..63
    if (lane < 32) out[bi * 96 + 64 + lane] = xA1;   // c t=64..95
    else out[24576 + bi * 96 + (lane - 32)] = xA1;   // d t=0..31
  } else if (wid == 1) {
    out[24576 + bi * 96 + 32 + lane] = xA0;          // d t=32..95
  }
}

extern "C" void kernel_launch(void* const* d_in, const int* in_sizes, int n_in,
                              void* d_out, int out_size, void* d_ws, size_t ws_size,
                              hipStream_t stream) {
  const float* price = (const float*)d_in[0];
  float* outp = (float*)d_out;
  hipLaunchKernelGGL(lp_solve_kernel, dim3(256), dim3(256), 0, stream, price, outp);
}